// Round 10
// baseline (2271.545 us; speedup 1.0000x reference)
//
#include <hip/hip_runtime.h>

#define BB 64
#define TT 512
#define HH 1024
#define OUTN 32000
#define NDOM 8              // 8 domains: 8 batch rows each, 1 XCD each (claimed)
#define NCB 32              // col-blocks per domain (32 cols each)
#define NWG 256
#define NTH 128             // 2 waves; wave wv owns 16 of the WG's 32 cols
#define SLOT (BB * HH * 2)  // 128 KB per ring slot
#define DSL 16384           // per-domain slice bytes (8 rows x 1024 x 2B)
#define FLAGS_OFF 1024      // [dom8][64] u32 monotonic per-wave flags
#define HBUF_OFF 4096       // ring of 3 slots (all init 0x00)
#define EMB_OFF (512 * 1024)
#define EMB_BYTES ((size_t)TT * BB * HH * 4)
// slot: [dom8][kb32][row8][col32] bf16; chunk = 16B = (row, 8 cols), one
// lane's dwordx4 (atomic unit). TAG: bits14 of u16[0],u16[1],u16[2] of each
// chunk = (step mod 8); tanh data has bit14==0 in every u16. Stale/racing
// data ALWAYS mismatches within a 24-step window -> retry, never corruption.

typedef __attribute__((ext_vector_type(8))) short s16x8;
typedef __attribute__((ext_vector_type(4))) float f32x4;
typedef __attribute__((ext_vector_type(4))) int i32x4;

static __device__ __forceinline__ unsigned short f2bf(float f) {
  union { float f; unsigned u; } a; a.f = f;
  unsigned r = a.u + 0x7fffu + ((a.u >> 16) & 1u);   // RNE
  return (unsigned short)(r >> 16);
}

static __device__ __forceinline__ float ftanh(float x) {
  float e = __expf(2.0f * x);
  return 1.0f - 2.0f * __builtin_amdgcn_rcpf(e + 1.0f);
}

#define ALD(idx, off_lit, vov, SCS)                                        \
  asm volatile("global_load_dwordx4 %0, %1, %2 offset:" #off_lit " " SCS   \
               : "=v"(areg[idx]) : "v"(vov), "s"(hprev) : "memory")

#define LDGRP(base, vov, SCS)                                              \
  ALD(base + 0, 0, vov, SCS);    ALD(base + 1, 512, vov, SCS);             \
  ALD(base + 2, 1024, vov, SCS); ALD(base + 3, 1536, vov, SCS);            \
  ALD(base + 4, 2048, vov, SCS); ALD(base + 5, 2560, vov, SCS);            \
  ALD(base + 6, 3072, vov, SCS); ALD(base + 7, 3584, vov, SCS);

#define ISSUEA(SCS)                                                        \
  { LDGRP(0, vo0, SCS) LDGRP(8, vo1, SCS) LDGRP(16, vo2, SCS)              \
    LDGRP(24, vo3, SCS) }

#define WAITV(n)                                                           \
  do { asm volatile("s_waitcnt vmcnt(" #n ")" ::: "memory");               \
       __builtin_amdgcn_sched_barrier(0); } while (0)

// verify tag + clear bits for group of 8 kb-blocks
#define CLRG(g)                                                            \
  { _Pragma("unroll") for (int j = 0; j < 8; ++j) {                        \
      unsigned u0 = (unsigned)areg[(g) * 8 + j][0];                        \
      unsigned u1 = (unsigned)areg[(g) * 8 + j][1];                        \
      bad |= ((u0 ^ want0) & 0x40004000u) | ((u1 ^ want1) & 0x4000u);      \
      areg[(g) * 8 + j][0] = (int)(u0 & ~0x40004000u);                     \
      areg[(g) * 8 + j][1] = (int)(u1 & ~0x4000u); } }

#define MFG(g)                                                             \
  { _Pragma("unroll") for (int j = 0; j < 8; ++j) {                        \
      union { i32x4 i; s16x8 s; } a_; a_.i = areg[(g) * 8 + j];            \
      s16x8 b_ = *reinterpret_cast<const s16x8*>(                          \
          &wlds[((((g) * 8 + j) * 2 + wv) * 64 + l) * 8]);                 \
      ac[j & 3] = __builtin_amdgcn_mfma_f32_16x16x32_bf16(                 \
          a_.s, b_, ac[j & 3], 0, 0, 0); } }

// emb[t][b][h] = Wxh[x[b][t]][h]  (f32) — pure streaming pre-gather
__global__ __launch_bounds__(256) void emb_gather(
    const int* __restrict__ x, const float* __restrict__ Wxh,
    float* __restrict__ emb) {
  int t = blockIdx.x >> 3;
  int b0 = (blockIdx.x & 7) * 8;
  int wv = threadIdx.x >> 6, l = threadIdx.x & 63;
  #pragma unroll
  for (int rr = 0; rr < 2; ++rr) {
    int b = b0 + wv * 2 + rr;
    int tok = x[b * TT + t];
    const float4* src = (const float4*)(Wxh + (size_t)tok * HH);
    float4* dst = (float4*)(emb + ((size_t)t * BB + b) * HH);
    #pragma unroll
    for (int c = 0; c < 4; ++c) dst[c * 64 + l] = src[c * 64 + l];
  }
}

__global__ __launch_bounds__(NTH, 1) void rnn_persist(
    const int* __restrict__ x, const float* __restrict__ Wxh,
    const float* __restrict__ Whh_w, const float* __restrict__ Whh_b,
    unsigned* __restrict__ ctl, char* __restrict__ ws,
    const float* __restrict__ embp, int use_emb) {
  const int tid = threadIdx.x;
  const int wv = tid >> 6;
  const int l = tid & 63;
  const int lr = l & 15;
  const int lq = l >> 4;
  const int lrc = lr < 8 ? lr : 7;   // A rows 8..15 duplicate row 7

  __shared__ __align__(16) unsigned short wlds[32 * 2 * 64 * 8];  // 64 KB
  __shared__ __align__(16) unsigned short epi[2 * 128];           // wave-private
  __shared__ unsigned sh_role;

  // ---- one-time role assignment: claim a slot on MY XCD (R7, verified) ----
  if (tid == 0) {
    unsigned xcc = (unsigned)__builtin_amdgcn_s_getreg(63508) & 7u; // XCC_ID
    unsigned slot = __hip_atomic_fetch_add(&ctl[16 + xcc], 1u,
                        __ATOMIC_RELAXED, __HIP_MEMORY_SCOPE_AGENT);
    __hip_atomic_fetch_add(&ctl[0], 1u, __ATOMIC_RELEASE,
                           __HIP_MEMORY_SCOPE_AGENT);
    int guard = 0;
    while (__hip_atomic_load(&ctl[0], __ATOMIC_ACQUIRE,
                             __HIP_MEMORY_SCOPE_AGENT) < (unsigned)NWG) {
      __builtin_amdgcn_s_sleep(8);
      if (++guard > (1 << 20)) break;
    }
    unsigned cnt[8];
    for (int d = 0; d < 8; ++d)
      cnt[d] = __hip_atomic_load(&ctl[16 + d], __ATOMIC_ACQUIRE,
                                 __HIP_MEMORY_SCOPE_AGENT);
    unsigned dm, cbv;
    if (slot < NCB) { dm = xcc; cbv = slot; }
    else {
      unsigned t = __hip_atomic_fetch_add(&ctl[1], 1u, __ATOMIC_RELAXED,
                                          __HIP_MEMORY_SCOPE_AGENT);
      unsigned acc2 = 0; dm = 0; cbv = 0;
      for (int d = 0; d < 8; ++d) {
        unsigned def = cnt[d] < NCB ? NCB - cnt[d] : 0;
        if (t < acc2 + def) { dm = d; cbv = cnt[d] + (t - acc2); break; }
        acc2 += def;
      }
    }
    unsigned pure = (cnt[dm] >= NCB) ? 1u : 0u;
    sh_role = (pure << 16) | (dm << 8) | cbv;
  }
  __syncthreads();
  const unsigned role = sh_role;
  const int dom = (role >> 8) & 0xff;
  const int cb = role & 0xff;
  bool sc0ok = ((role >> 16) != 0);   // sticky fast path; degrades, never returns

  char* hbuf = ws + HBUF_OFF;
  unsigned* flagsD = (unsigned*)(ws + FLAGS_OFF) + dom * 64;
  const int mycol = cb * 32 + wv * 16 + lr;
  const unsigned vo0 = (unsigned)(lrc * 64 + lq * 16);
  const unsigned vo1 = vo0 + 4096, vo2 = vo0 + 8192, vo3 = vo0 + 12288;

  // ---- one-time B pack: Whh^T slice -> LDS, MFMA B-fragment order ----
  for (int e = tid; e < 32 * 2 * 64; e += NTH) {
    int kb = e >> 7;
    int nt = (e >> 6) & 1;
    int ln = e & 63;
    int col = cb * 32 + nt * 16 + (ln & 15);
    int k0 = kb * 32 + (ln >> 4) * 8;
    const float* src = Whh_w + (size_t)col * HH + k0;
    union { unsigned short u[8]; i32x4 v; } pk;
    #pragma unroll
    for (int j = 0; j < 8; ++j) pk.u[j] = f2bf(src[j]);
    *reinterpret_cast<i32x4*>(&wlds[(size_t)e * 8]) = pk.v;
  }
  const float bias = Whh_b[mycol];
  __syncthreads();

  int xrow[4], xv[4];
  #pragma unroll
  for (int i = 0; i < 4; ++i) {
    int rr = lq * 4 + i; if (rr > 7) rr = 7;
    xrow[i] = (dom * 8 + rr) * TT;
    xv[i] = x[xrow[i]];
  }

  for (int s = 0; s < TT; ++s) {
    const char* hprev = hbuf + (s % 3) * SLOT + dom * DSL;
    char* hcur = hbuf + ((s + 1) % 3) * SLOT + dom * DSL;
    const unsigned tagw = (unsigned)(s & 7);
    const unsigned want0 = ((tagw & 1) << 14) | (((tagw >> 1) & 1) << 30);
    const unsigned want1 = ((tagw >> 2) & 1) << 14;

    float evu[4];
    if (!use_emb) {   // fallback: ev gather now (hides under poll)
      #pragma unroll
      for (int i = 0; i < 4; ++i) evu[i] = Wxh[(size_t)xv[i] * HH + mycol];
    }

    // ---- poll: 64 wave-flags of my domain must reach s ----
    if (s > 0) {
      const unsigned* fp = flagsD + l;
      bool done = false;
      if (sc0ok) {   // fast path: own-XCD L2 (validity guaranteed by tags)
        int plimit = (s < 3) ? 512 : 96;
        unsigned fv;
        for (int it = 0; it < plimit; ++it) {
          asm volatile("global_load_dword %0, %1, off sc0\n\t"
                       "s_waitcnt vmcnt(0)"
                       : "=v"(fv) : "v"(fp) : "memory");
          if (__all(fv >= (unsigned)s)) { done = true; break; }
        }
        if (!done && s >= 3) sc0ok = false;   // sticky degrade
      }
      if (!done) {   // depth-2 pipelined device-scope poll
        unsigned f0, f1; int guard = 0;
        asm volatile("global_load_dword %0, %1, off sc1"
                     : "=v"(f0) : "v"(fp) : "memory");
        for (;;) {
          asm volatile("global_load_dword %0, %1, off sc1"
                       : "=v"(f1) : "v"(fp) : "memory");
          asm volatile("s_waitcnt vmcnt(1)" ::: "memory");
          if (__all(f0 >= (unsigned)s)) break;
          asm volatile("global_load_dword %0, %1, off sc1"
                       : "=v"(f0) : "v"(fp) : "memory");
          asm volatile("s_waitcnt vmcnt(1)" ::: "memory");
          if (__all(f1 >= (unsigned)s)) break;
          if (++guard > (1 << 16)) break;   // safety valve
        }
      }
      __builtin_amdgcn_sched_barrier(0);
    }

    // ---- one-shot A-load (16 KB) + aux loads; gates tolerate stale polls ----
    i32x4 areg[32];
    if (sc0ok) { ISSUEA("sc0") } else { ISSUEA("sc1") }
    if (use_emb) {
      #pragma unroll
      for (int i = 0; i < 4; ++i) {
        int rr = lq * 4 + i; if (rr > 7) rr = 7;
        evu[i] = embp[((size_t)s * BB + dom * 8 + rr) * HH + mycol];
      }
    } else {
      int snext = (s + 1 < TT) ? (s + 1) : s;
      #pragma unroll
      for (int i = 0; i < 4; ++i) xv[i] = x[xrow[i] + snext];
    }

    unsigned bad = 0;
    f32x4 ac[4];
    #pragma unroll
    for (int c = 0; c < 4; ++c) ac[c] = (f32x4){0.f, 0.f, 0.f, 0.f};
    WAITV(28); CLRG(0); MFG(0);
    WAITV(20); CLRG(1); MFG(1);
    WAITV(12); CLRG(2); MFG(2);
    WAITV(4);  CLRG(3); MFG(3);
    WAITV(0);

    if (!__all(bad == 0)) {          // race or stale cache
      if (sc0ok) {                   // one sc0 retry (transient race)
        bad = 0;
        ISSUEA("sc0")
        asm volatile("s_waitcnt vmcnt(0)" ::: "memory");
        __builtin_amdgcn_sched_barrier(0);
        CLRG(0); CLRG(1); CLRG(2); CLRG(3);
      }
      if (!__all(bad == 0)) {        // persistent -> device scope + degrade
        sc0ok = false;
        int gr = 0;
        for (;;) {
          bad = 0;
          ISSUEA("sc1")
          asm volatile("s_waitcnt vmcnt(0)" ::: "memory");
          __builtin_amdgcn_sched_barrier(0);
          CLRG(0); CLRG(1); CLRG(2); CLRG(3);
          if (__all(bad == 0)) break;
          if (++gr > (1 << 15)) break;   // never hard-wedge
        }
      }
      #pragma unroll
      for (int c = 0; c < 4; ++c) ac[c] = (f32x4){0.f, 0.f, 0.f, 0.f};
      MFG(0); MFG(1); MFG(2); MFG(3);
    }
    f32x4 acc = (ac[0] + ac[1]) + (ac[2] + ac[3]);

    // ---- epilogue (wave-private, no __syncthreads) ----
    if (lq < 2) {
      #pragma unroll
      for (int i = 0; i < 4; ++i) {
        float v = ftanh(acc[i] + evu[i] + bias);
        epi[wv * 128 + (lq * 4 + i) * 16 + lr] = f2bf(v);
      }
    }
    asm volatile("s_waitcnt lgkmcnt(0)" ::: "memory");
    __builtin_amdgcn_sched_barrier(0);
    {
      const unsigned tn = (unsigned)((s + 1) & 7);
      const unsigned tb0 = ((tn & 1) << 14) | (((tn >> 1) & 1) << 30);
      const unsigned tb1 = ((tn >> 2) & 1) << 14;
      if (l < 16) {   // 8 rows x this wave's 16 cols = 16 chunks
        int r = l >> 1, cg = l & 1;
        i32x4 v = *reinterpret_cast<const i32x4*>(&epi[wv * 128 + r * 16 + cg * 8]);
        v[0] |= (int)tb0;
        v[1] |= (int)tb1;
        char* dst = hcur + cb * 512 + r * 64 + wv * 32 + cg * 16;
        asm volatile("global_store_dwordx4 %0, %1, off sc1"
                     :: "v"(dst), "v"(v) : "memory");
      }
      if (l == 0) {   // per-wave flag, no ack (tags catch the rare race)
        unsigned sv = (unsigned)(s + 1);
        asm volatile("global_store_dword %0, %1, off sc1"
                     :: "v"(flagsD + cb * 2 + wv), "v"(sv) : "memory");
      }
    }
  }
}

// out[64][32000] = h_final @ Why^T + Why_b; h_512 = slot 2 (512%3), tag 0 -> clean
__global__ __launch_bounds__(256) void rnn_proj(
    const char* __restrict__ hfin, const float* __restrict__ Why_w,
    const float* __restrict__ Why_b, float* __restrict__ out) {
  const int tid = threadIdx.x;
  const int w = tid >> 6;
  const int l = tid & 63;
  const int lr = l & 15;
  const int lq = l >> 4;
  const int nbase = blockIdx.x * 128;
  const int row = w * 16 + lr;

  f32x4 acc[8];
  #pragma unroll
  for (int nt = 0; nt < 8; ++nt) acc[nt] = (f32x4){0.f, 0.f, 0.f, 0.f};

  const char* abase = hfin + (size_t)(row >> 3) * DSL + (row & 7) * 64 + lq * 16;
  for (int kb = 0; kb < 32; ++kb) {
    s16x8 a = *reinterpret_cast<const s16x8*>(abase + kb * 512);
    #pragma unroll
    for (int nt = 0; nt < 8; ++nt) {
      int n = nbase + nt * 16 + lr;
      const float* wp = Why_w + (size_t)n * HH + kb * 32 + lq * 8;
      union { unsigned short u[8]; s16x8 v; } bb;
      #pragma unroll
      for (int j = 0; j < 8; ++j) bb.u[j] = f2bf(wp[j]);
      acc[nt] = __builtin_amdgcn_mfma_f32_16x16x32_bf16(a, bb.v, acc[nt], 0, 0, 0);
    }
  }
  #pragma unroll
  for (int nt = 0; nt < 8; ++nt) {
    int n = nbase + nt * 16 + lr;
    float bv = Why_b[n];
    #pragma unroll
    for (int i = 0; i < 4; ++i) {
      int b = w * 16 + lq * 4 + i;
      out[(size_t)b * OUTN + n] = acc[nt][i] + bv;
    }
  }
}

extern "C" void kernel_launch(void* const* d_in, const int* in_sizes, int n_in,
                              void* d_out, int out_size, void* d_ws, size_t ws_size,
                              hipStream_t stream) {
  const int* x = (const int*)d_in[0];
  const float* Wxh = (const float*)d_in[1];
  const float* Whh_w = (const float*)d_in[2];
  const float* Whh_b = (const float*)d_in[3];
  const float* Why_w = (const float*)d_in[4];
  const float* Why_b = (const float*)d_in[5];
  float* out = (float*)d_out;

  char* ws = (char*)d_ws;
  unsigned* ctl = (unsigned*)d_ws;
  char* hbuf = ws + HBUF_OFF;
  float* emb = (float*)(ws + EMB_OFF);
  int use_emb = (ws_size >= EMB_OFF + EMB_BYTES) ? 1 : 0;

  // ctl + flags + ALL THREE slots -> 0 (tag scheme makes all-zero valid init)
  hipMemsetAsync(ws, 0x00, HBUF_OFF + 3 * SLOT, stream);
  if (use_emb) emb_gather<<<TT * 8, 256, 0, stream>>>(x, Wxh, emb);
  rnn_persist<<<NWG, NTH, 0, stream>>>(x, Wxh, Whh_w, Whh_b, ctl, ws, emb, use_emb);
  rnn_proj<<<OUTN / 128, 256, 0, stream>>>(hbuf + 2 * SLOT, Why_w, Why_b, out);
}

// Round 11
// 2245.213 us; speedup vs baseline: 1.0117x; 1.0117x over previous
//
#include <hip/hip_runtime.h>

#define BB 64
#define TT 512
#define HH 1024
#define OUTN 32000
#define NDOM 4              // 4 independent domains: 16 batch rows each
#define NCB 32              // col-blocks per domain (32 cols each)
#define NWG (NDOM * NCB)    // 128 workgroups
#define NTH 128             // 2 waves; wave wv owns 16 of the WG's 32 cols
#define SLOT (BB * HH * 2)  // 128 KB per ring slot
#define FLAGS_BYTES 4096
#define HBUF_OFF FLAGS_BYTES
#define EMB_OFF (512 * 1024)
#define EMB_BYTES ((size_t)TT * BB * HH * 4)
// ws: [flags 4KB][ring of 3 slots x 128KB]...[emb slab at 512KB]
// slot: [dom4][kb32][row16][col32] bf16; chunk = 16B = (row, 8 cols), one
// lane's dwordx4 (atomic unit). TAG: bit14 of u16[0],u16[1],u16[2] of each
// chunk = (step mod 8); tanh data has bit14==0 in every u16. All-zero init
// = tag 0 = valid h_0. Stale data mismatches within a 24-step window.
// flags[dom*64 + cb*2 + wv]: monotonic per-wave counters (fallback poll only).

typedef __attribute__((ext_vector_type(8))) short s16x8;
typedef __attribute__((ext_vector_type(4))) float f32x4;
typedef __attribute__((ext_vector_type(4))) int i32x4;

static __device__ __forceinline__ unsigned short f2bf(float f) {
  union { float f; unsigned u; } a; a.f = f;
  unsigned r = a.u + 0x7fffu + ((a.u >> 16) & 1u);   // RNE
  return (unsigned short)(r >> 16);
}

static __device__ __forceinline__ float ftanh(float x) {
  float e = __expf(2.0f * x);
  return 1.0f - 2.0f * __builtin_amdgcn_rcpf(e + 1.0f);
}

#define ALD(idx, off_lit, vov)                                            \
  asm volatile("global_load_dwordx4 %0, %1, %2 offset:" #off_lit " sc1"   \
               : "=v"(areg[idx]) : "v"(vov), "s"(hprev) : "memory")

// all 32 A-chunk loads, areg[kb] <-> kb, exact vmcnt accounting
#define ISSUEA                                                             \
  ALD(0,0,vo0);  ALD(1,1024,vo0);  ALD(2,2048,vo0);  ALD(3,3072,vo0);      \
  ALD(4,0,vo1);  ALD(5,1024,vo1);  ALD(6,2048,vo1);  ALD(7,3072,vo1);      \
  ALD(8,0,vo2);  ALD(9,1024,vo2);  ALD(10,2048,vo2); ALD(11,3072,vo2);     \
  ALD(12,0,vo3); ALD(13,1024,vo3); ALD(14,2048,vo3); ALD(15,3072,vo3);     \
  ALD(16,0,vo4); ALD(17,1024,vo4); ALD(18,2048,vo4); ALD(19,3072,vo4);     \
  ALD(20,0,vo5); ALD(21,1024,vo5); ALD(22,2048,vo5); ALD(23,3072,vo5);     \
  ALD(24,0,vo6); ALD(25,1024,vo6); ALD(26,2048,vo6); ALD(27,3072,vo6);     \
  ALD(28,0,vo7); ALD(29,1024,vo7); ALD(30,2048,vo7); ALD(31,3072,vo7);

#define WAITV(n)                                                           \
  do { asm volatile("s_waitcnt vmcnt(" #n ")" ::: "memory");               \
       __builtin_amdgcn_sched_barrier(0); } while (0)

// verify 3-bit tag + clear bits for a group of 8 kb-blocks
#define CLRG(g)                                                            \
  { _Pragma("unroll") for (int j = 0; j < 8; ++j) {                        \
      unsigned u0 = (unsigned)areg[(g) * 8 + j][0];                        \
      unsigned u1 = (unsigned)areg[(g) * 8 + j][1];                        \
      bad |= ((u0 ^ want0) & 0x40004000u) | ((u1 ^ want1) & 0x4000u);      \
      areg[(g) * 8 + j][0] = (int)(u0 & ~0x40004000u);                     \
      areg[(g) * 8 + j][1] = (int)(u1 & ~0x4000u); } }

// MFMA one group of 8 kb-blocks, fixed order, 4 independent chains
#define MFG(g)                                                             \
  { _Pragma("unroll") for (int j = 0; j < 8; ++j) {                        \
      union { i32x4 i; s16x8 s; } a_; a_.i = areg[(g) * 8 + j];            \
      s16x8 b_ = *reinterpret_cast<const s16x8*>(                          \
          &wlds[((((g) * 8 + j) * 2 + wv) * 64 + l) * 8]);                 \
      ac[j & 3] = __builtin_amdgcn_mfma_f32_16x16x32_bf16(                 \
          a_.s, b_, ac[j & 3], 0, 0, 0); } }

// emb[t][b][h] = Wxh[x[b][t]][h] (f32) — streaming pre-gather
__global__ __launch_bounds__(256) void emb_gather(
    const int* __restrict__ x, const float* __restrict__ Wxh,
    float* __restrict__ emb) {
  int t = blockIdx.x >> 3;
  int b0 = (blockIdx.x & 7) * 8;
  int wv = threadIdx.x >> 6, l = threadIdx.x & 63;
  #pragma unroll
  for (int rr = 0; rr < 2; ++rr) {
    int b = b0 + wv * 2 + rr;
    int tok = x[b * TT + t];
    const float4* src = (const float4*)(Wxh + (size_t)tok * HH);
    float4* dst = (float4*)(emb + ((size_t)t * BB + b) * HH);
    #pragma unroll
    for (int c = 0; c < 4; ++c) dst[c * 64 + l] = src[c * 64 + l];
  }
}

__global__ __launch_bounds__(NTH, 1) void rnn_persist(
    const int* __restrict__ x, const float* __restrict__ Wxh,
    const float* __restrict__ Whh_w, const float* __restrict__ Whh_b,
    unsigned* __restrict__ flags, char* __restrict__ hbuf,
    const float* __restrict__ embp, int use_emb) {
  const int g = blockIdx.x;
  const int dom = g >> 5;          // batch rows [16*dom, +16)
  const int cb = g & 31;           // cols [32*cb, +32)
  const int tid = threadIdx.x;
  const int wv = tid >> 6;
  const int l = tid & 63;
  const int lr = l & 15;
  const int lq = l >> 4;

  __shared__ __align__(16) unsigned short wlds[32 * 2 * 64 * 8];  // 64 KB B-frags
  __shared__ __align__(16) unsigned short epi[2 * 256];           // wave-private

  // One-time B pack (MFMA B-fragment order)
  for (int e = tid; e < 32 * 2 * 64; e += NTH) {
    int kb = e >> 7;
    int nt = (e >> 6) & 1;
    int ln = e & 63;
    int col = cb * 32 + nt * 16 + (ln & 15);
    int k0 = kb * 32 + (ln >> 4) * 8;
    const float* src = Whh_w + (size_t)col * HH + k0;
    union { unsigned short u[8]; i32x4 v; } pk;
    #pragma unroll
    for (int j = 0; j < 8; ++j) pk.u[j] = f2bf(src[j]);
    *reinterpret_cast<i32x4*>(&wlds[(size_t)e * 8]) = pk.v;
  }
  const int mycol = cb * 32 + wv * 16 + lr;
  const float bias = Whh_b[mycol];
  __syncthreads();   // only barrier in the kernel

  int xrow[4], xv[4];
  #pragma unroll
  for (int i = 0; i < 4; ++i) {
    xrow[i] = (dom * 16 + lq * 4 + i) * TT;
    xv[i] = x[xrow[i]];
  }

  unsigned* flagsD = flags + dom * 64;
  const unsigned vo0 = (unsigned)(lr * 64 + lq * 16);
  const unsigned vo1 = vo0 + 4096, vo2 = vo0 + 8192, vo3 = vo0 + 12288;
  const unsigned vo4 = vo0 + 16384, vo5 = vo0 + 20480, vo6 = vo0 + 24576,
                 vo7 = vo0 + 28672;

  for (int s = 0; s < TT; ++s) {
    const char* hprev = hbuf + (s % 3) * SLOT + dom * 32768;
    char* hcur = hbuf + ((s + 1) % 3) * SLOT + dom * 32768;
    const unsigned tagw = (unsigned)(s & 7);
    const unsigned want0 = ((tagw & 1) << 14) | (((tagw >> 1) & 1) << 30);
    const unsigned want1 = ((tagw >> 2) & 1) << 14;

    // --- SPECULATIVE A-load: no poll; tags prove validity on arrival ---
    i32x4 areg[32];
    ISSUEA;

    // ev loads (pinned between memory-clobber asm: issue here, land by WAITV(0))
    float evu[4];
    if (use_emb) {
      #pragma unroll
      for (int i = 0; i < 4; ++i)
        evu[i] = embp[((size_t)s * BB + dom * 16 + lq * 4 + i) * HH + mycol];
    } else {
      #pragma unroll
      for (int i = 0; i < 4; ++i) evu[i] = Wxh[(size_t)xv[i] * HH + mycol];
      int snext = (s + 1 < TT) ? (s + 1) : s;
      #pragma unroll
      for (int i = 0; i < 4; ++i) xv[i] = x[xrow[i] + snext];
    }

    unsigned bad = 0;
    f32x4 ac[4];
    #pragma unroll
    for (int c = 0; c < 4; ++c) ac[c] = (f32x4){0.f, 0.f, 0.f, 0.f};
    WAITV(28); CLRG(0); MFG(0);
    WAITV(20); CLRG(1); MFG(1);
    WAITV(12); CLRG(2); MFG(2);
    WAITV(4);  CLRG(3); MFG(3);
    WAITV(0);

    if (!__all(bad == 0)) {
      // --- fallback: cheap flag poll (128B/iter), then one reload ---
      if (s > 0) {
        const unsigned* fp = flagsD + l;
        int guard = 0;
        unsigned fv;
        do {
          asm volatile("global_load_dword %0, %1, off sc1\n\t"
                       "s_waitcnt vmcnt(0)"
                       : "=v"(fv) : "v"(fp) : "memory");
          if (++guard > (1 << 17)) break;   // safety valve
        } while (!__all(fv >= (unsigned)s));
        __builtin_amdgcn_sched_barrier(0);
      }
      int gr = 0;
      for (;;) {
        bad = 0;
        ISSUEA;
        asm volatile("s_waitcnt vmcnt(0)" ::: "memory");
        __builtin_amdgcn_sched_barrier(0);
        CLRG(0); CLRG(1); CLRG(2); CLRG(3);
        if (__all(bad == 0)) break;
        if (++gr > (1 << 15)) break;      // never hard-wedge
      }
      #pragma unroll
      for (int c = 0; c < 4; ++c) ac[c] = (f32x4){0.f, 0.f, 0.f, 0.f};
      MFG(0); MFG(1); MFG(2); MFG(3);
    }
    f32x4 acc = (ac[0] + ac[1]) + (ac[2] + ac[3]);

    // --- epilogue (wave-private LDS repack; C/D col=lane&15, row=(lane>>4)*4+i)
    #pragma unroll
    for (int i = 0; i < 4; ++i) {
      float v = ftanh(acc[i] + evu[i] + bias);
      epi[wv * 256 + (lq * 4 + i) * 16 + lr] = f2bf(v);
    }
    asm volatile("s_waitcnt lgkmcnt(0)" ::: "memory");
    __builtin_amdgcn_sched_barrier(0);

    // --- wave stores its 32 chunks (16 rows x its 16 cols), tag-embedded ---
    {
      const unsigned tn = (unsigned)((s + 1) & 7);
      const unsigned tb0 = ((tn & 1) << 14) | (((tn >> 1) & 1) << 30);
      const unsigned tb1 = ((tn >> 2) & 1) << 14;
      if (l < 32) {
        int r = l >> 1, cg = l & 1;
        i32x4 v = *reinterpret_cast<const i32x4*>(&epi[wv * 256 + r * 16 + cg * 8]);
        v[0] |= (int)tb0;
        v[1] |= (int)tb1;
        char* dst = hcur + cb * 1024 + r * 64 + wv * 32 + cg * 16;
        asm volatile("global_store_dwordx4 %0, %1, off sc1"
                     :: "v"(dst), "v"(v) : "memory");
      }
      if (l == 0) {   // per-wave flag, no ack (tags catch flag-ahead races)
        unsigned sv = (unsigned)(s + 1);
        asm volatile("global_store_dword %0, %1, off sc1"
                     :: "v"(flagsD + cb * 2 + wv), "v"(sv) : "memory");
      }
    }
  }
}

// out[64][32000] = h_final @ Why^T + Why_b; h_512 = slot 2 (512%3==2),
// tag = 512&7 = 0 -> data clean, no fixup. float4-vectorized Why loads.
__global__ __launch_bounds__(256) void rnn_proj(
    const char* __restrict__ hfin, const float* __restrict__ Why_w,
    const float* __restrict__ Why_b, float* __restrict__ out) {
  const int tid = threadIdx.x;
  const int w = tid >> 6;
  const int l = tid & 63;
  const int lr = l & 15;
  const int lq = l >> 4;
  const int nbase = blockIdx.x * 128;
  const int row = w * 16 + lr;

  f32x4 acc[8];
  #pragma unroll
  for (int nt = 0; nt < 8; ++nt) acc[nt] = (f32x4){0.f, 0.f, 0.f, 0.f};

  const char* abase = hfin + (size_t)(row >> 4) * 32768 + (row & 15) * 64 + lq * 16;
  for (int kb = 0; kb < 32; ++kb) {
    s16x8 a = *reinterpret_cast<const s16x8*>(abase + kb * 1024);
    #pragma unroll
    for (int nt = 0; nt < 8; ++nt) {
      int n = nbase + nt * 16 + lr;
      const float4* wp = (const float4*)(Why_w + (size_t)n * HH + kb * 32 + lq * 8);
      float4 w0 = wp[0];
      float4 w1 = wp[1];
      union { unsigned short u[8]; s16x8 v; } bb;
      bb.u[0] = f2bf(w0.x); bb.u[1] = f2bf(w0.y);
      bb.u[2] = f2bf(w0.z); bb.u[3] = f2bf(w0.w);
      bb.u[4] = f2bf(w1.x); bb.u[5] = f2bf(w1.y);
      bb.u[6] = f2bf(w1.z); bb.u[7] = f2bf(w1.w);
      acc[nt] = __builtin_amdgcn_mfma_f32_16x16x32_bf16(a, bb.v, acc[nt], 0, 0, 0);
    }
  }
  #pragma unroll
  for (int nt = 0; nt < 8; ++nt) {
    int n = nbase + nt * 16 + lr;
    float bv = Why_b[n];
    #pragma unroll
    for (int i = 0; i < 4; ++i) {
      int b = w * 16 + lq * 4 + i;
      out[(size_t)b * OUTN + n] = acc[nt][i] + bv;
    }
  }
}

extern "C" void kernel_launch(void* const* d_in, const int* in_sizes, int n_in,
                              void* d_out, int out_size, void* d_ws, size_t ws_size,
                              hipStream_t stream) {
  const int* x = (const int*)d_in[0];
  const float* Wxh = (const float*)d_in[1];
  const float* Whh_w = (const float*)d_in[2];
  const float* Whh_b = (const float*)d_in[3];
  const float* Why_w = (const float*)d_in[4];
  const float* Why_b = (const float*)d_in[5];
  float* out = (float*)d_out;

  char* ws = (char*)d_ws;
  unsigned* flags = (unsigned*)d_ws;
  char* hbuf = ws + HBUF_OFF;
  float* emb = (float*)(ws + EMB_OFF);
  int use_emb = (ws_size >= EMB_OFF + EMB_BYTES) ? 1 : 0;

  // flags + all 3 slots -> 0 (tag scheme: all-zero = valid h_0, stale elsewhere)
  hipMemsetAsync(ws, 0x00, HBUF_OFF + 3 * SLOT, stream);
  if (use_emb) emb_gather<<<TT * 8, 256, 0, stream>>>(x, Wxh, emb);
  rnn_persist<<<NWG, NTH, 0, stream>>>(x, Wxh, Whh_w, Whh_b, flags, hbuf,
                                       emb, use_emb);
  rnn_proj<<<OUTN / 128, 256, 0, stream>>>(hbuf + 2 * SLOT, Why_w, Why_b, out);
}